// Round 6
// baseline (349.464 us; speedup 1.0000x reference)
//
#include <hip/hip_runtime.h>
#include <hip/hip_bf16.h>
#include <cstddef>

// Problem constants
#define NB 256   // batch
#define RR 32    // rooms
#define WW 8     // room width
#define HH 6     // room height
#define MXY 72   // map extent
#define EMB 6
#define CIN1 16  // 9 + 1 + 6

typedef __bf16 bf16x8 __attribute__((ext_vector_type(8)));
typedef float floatx4 __attribute__((ext_vector_type(4)));

// --- Workspace layout (byte offsets) ---------------------------------------
// Conv weights packed per-kstep (2KB per kstep per ntile-group layout):
//   W1F: 13+1 ksteps [0,57344) ; W2F: 18 [57344,131072) ; W3F: 18 [131072,..)
static const size_t B_W1F  = 0;
static const size_t B_W2F  = 57344;
static const size_t B_W3F  = 131072;
static const size_t B_RAUX = 204800;    // room masks (32 u64)
static const size_t B_RINV = 205056;    // 1/room_size (32 f32)
static const size_t B_HEAD = 205312;    // fp32 head weights, 122880 floats
static const size_t F_WR1T = 0;         // (64,128)
static const size_t F_WR2T = 8192;      // (128,128)
static const size_t F_F1T  = 24576;     // (128,256)
static const size_t F_F2T  = 57344;     // (256,256)
static const size_t B_FEAT = 696832;    // (256,32,64) f32 = 2 MB
static const size_t B_CHUNK = 2793984;  // X buffer
static const size_t PERN_BYTES = 165888;  // X bf16 5184*16*2

__device__ inline short f2b(float f) {
    unsigned u = __builtin_bit_cast(unsigned, f);
    unsigned r = (u + 0x7fffu + ((u >> 16) & 1u)) >> 16;
    return (short)r;
}

// ---------------------------------------------------------------------------
// Prep: conv weights fp32 -> bf16 B-fragment order; head weights transposed.
// Fragment order: [kk][ntile][lane][j] ; virtual k = kk*32 + (lane>>4)*8 + j
// oc = ntile*16 + (lane&15).
// conv1: (tap,ci) natural. conv2/3: position cp -> channel (cp>>2)+(cp&3)*16
// (paired-channel layout Y1/Y2 are written in).
// ---------------------------------------------------------------------------
__global__ void prep_weights(const float* __restrict__ w1, const float* __restrict__ w2,
                             const float* __restrict__ w3, const float* __restrict__ wr1,
                             const float* __restrict__ wr2, const float* __restrict__ wf1,
                             const float* __restrict__ wf2, char* __restrict__ ws)
{
    short* W1F = (short*)(ws + B_W1F);
    short* W2F = (short*)(ws + B_W2F);
    short* W3F = (short*)(ws + B_W3F);
    float* HEAD = (float*)(ws + B_HEAD);

    int idx = blockIdx.x * 256 + threadIdx.x;
    if (idx < 28672) {  // conv1: 14 ksteps (padded), CIN=16, taps 0..24 real
        int j = idx & 7, lane = (idx >> 3) & 63, nt = (idx >> 9) & 3, kk = idx >> 11;
        int k = kk * 32 + (lane >> 4) * 8 + j;
        int oc = nt * 16 + (lane & 15);
        int tap = k >> 4, ci = k & 15;
        float v = (tap < 25) ? w1[(oc * 16 + ci) * 25 + tap] : 0.f;
        W1F[idx] = f2b(v);
        return;
    }
    idx -= 28672;
    if (idx < 36864) {  // conv2: 18 ksteps, CIN=64, 9 taps, permuted ci
        int j = idx & 7, lane = (idx >> 3) & 63, nt = (idx >> 9) & 3, kk = idx >> 11;
        int k = kk * 32 + (lane >> 4) * 8 + j;
        int oc = nt * 16 + (lane & 15);
        int tap = k >> 6, cp = k & 63;
        int ci = (cp >> 2) + (cp & 3) * 16;
        W2F[idx] = f2b(w2[(oc * 64 + ci) * 9 + tap]);
        return;
    }
    idx -= 36864;
    if (idx < 36864) {  // conv3, permuted ci
        int j = idx & 7, lane = (idx >> 3) & 63, nt = (idx >> 9) & 3, kk = idx >> 11;
        int k = kk * 32 + (lane >> 4) * 8 + j;
        int oc = nt * 16 + (lane & 15);
        int tap = k >> 6, cp = k & 63;
        int ci = (cp >> 2) + (cp & 3) * 16;
        W3F[idx] = f2b(w3[(oc * 64 + ci) * 9 + tap]);
        return;
    }
    idx -= 36864;
    if (idx < 8192)  { int o = idx & 127, c = idx >> 7; HEAD[F_WR1T + idx] = wr1[o * 64 + c]; return; }
    idx -= 8192;
    if (idx < 16384) { int o = idx & 127, c = idx >> 7; HEAD[F_WR2T + idx] = wr2[o * 128 + c]; return; }
    idx -= 16384;
    if (idx < 32768) { int o = idx & 255, c = idx >> 8; HEAD[F_F1T + idx] = wf1[o * 128 + c]; return; }
    idx -= 32768;
    if (idx < 65536) { int o = idx & 255, c = idx >> 8; HEAD[F_F2T + idx] = wf2[o * 256 + c]; return; }
}

// Room footprint bitmasks (48 bits) + 1/room_size.
__global__ void prep_rooms(const float* __restrict__ rt, char* __restrict__ ws)
{
    int r = threadIdx.x;
    if (r >= RR) return;
    unsigned long long m = 0ull;
    int cnt = 0;
    for (int j = 0; j < WW * HH; ++j)
        if (rt[r * 9 * 48 + j] != 0.f) { m |= (1ull << j); ++cnt; }
    ((unsigned long long*)(ws + B_RAUX))[r] = m;
    ((float*)(ws + B_RINV))[r] = 1.f / (float)cnt;
}

// ---------------------------------------------------------------------------
// Build X (nc, 72, 72, 16) NHWC bf16 — GATHER style.
// ---------------------------------------------------------------------------
__global__ __launch_bounds__(256) void build_x(const int* __restrict__ pos,
                                               const float* __restrict__ rt,
                                               const float* __restrict__ emb,
                                               short* __restrict__ X, int n0)
{
    const int nl = blockIdx.y;
    const int n = n0 + nl;
    const int p = blockIdx.x * 256 + threadIdx.x;

    __shared__ int s_px[RR], s_py[RR];
    __shared__ float s_emb[RR * EMB];
    if (threadIdx.x < RR) {
        s_px[threadIdx.x] = pos[(n * RR + threadIdx.x) * 2 + 0];
        s_py[threadIdx.x] = pos[(n * RR + threadIdx.x) * 2 + 1];
    }
    for (int i = threadIdx.x; i < RR * EMB; i += 256) s_emb[i] = emb[i];
    __syncthreads();
    if (p >= MXY * MXY) return;

    const int gx = p / MXY, gy = p - (p / MXY) * MXY;

    float acc[16];
#pragma unroll
    for (int c = 0; c < 16; ++c) acc[c] = 0.f;
    acc[9] = 1.f;

    for (int r = 0; r < RR; ++r) {
        int w = gx - s_px[r], h = gy - s_py[r];
        if ((unsigned)w < (unsigned)WW && (unsigned)h < (unsigned)HH) {
            int j = w * HH + h;
            const float* rr = rt + r * 9 * 48;
#pragma unroll
            for (int c = 0; c < 9; ++c) acc[c] += rr[c * 48 + j];
            float m = rr[j];  // channel 0 = room_map
#pragma unroll
            for (int e = 0; e < EMB; ++e) acc[10 + e] += s_emb[r * EMB + e] * m;
        }
    }

    short o[16];
#pragma unroll
    for (int c = 0; c < 16; ++c) o[c] = f2b(acc[c]);
    short* dst = X + ((size_t)nl * (MXY * MXY) + p) * CIN1;
    *reinterpret_cast<uint4*>(dst) = *reinterpret_cast<uint4*>(o);
    *reinterpret_cast<uint4*>(dst + 8) = *reinterpret_cast<uint4*>(o + 8);
}

// ---------------------------------------------------------------------------
// ROUND-6 FUSED CONV CHAIN — consolidation of the measured budget:
//  * B frags in REGISTERS from global (round-3 style): L1 dedups the 4-wave
//    redundancy at zero LDS-pipe cost. (Round 4/5 put B in LDS -> LDS pipe
//    ~75% busy became the wall; round 5 proved L2 was never the limit.)
//  * 1 sample/block, LDS 29KB -> 5 blocks/CU TLP (round 5's 2 blk/CU convoy
//    at 25 barrier-phases is gone: 4 barriers per block total).
//  * b64 paired-channel epilogue stores (channel c at pos (c&15)*4+(c>>4),
//    conv2/3 weights pre-permuted to match) — round 3 burned 15.4M conflict
//    cycles on scalar b16 epilogue stores.
//  * conv2 balanced: waves own tiles 0-3; tile 4 is n-split across waves
//    (B4 frag via wave-uniform address, rule #20 safe) -> 5 MFMA/kstep/wave.
//  * B ping-pong depth 1 (+ B4 pong) chained across conv stages.
// ---------------------------------------------------------------------------
__global__ __launch_bounds__(256, 5) void fused_conv(const short* __restrict__ X,
    const short* __restrict__ wAll, const float* __restrict__ bc1,
    const float* __restrict__ bc2, const float* __restrict__ bc3,
    const int* __restrict__ pos, const unsigned long long* __restrict__ rmask,
    float* __restrict__ feat, int n0)
{
    __shared__ __align__(16) short s_Y1[120 * 72];  // 17280 B, paired-channel
    __shared__ __align__(16) short s_u[80 * 72];    // X[224][24] then Y2[80][72]
    __shared__ float s_feat[64];

    const int tid = threadIdx.x;
    const int lane = tid & 63;
    const int wv = tid >> 6;
    const int ml = lane & 15;
    const int q = lane >> 4;
    const int room = blockIdx.x;
    const int nl = blockIdx.y;
    const int n = n0 + nl;

    const int px = pos[(n * RR + room) * 2 + 0];
    const int py = pos[(n * RR + room) * 2 + 1];

    const short* W1F = wAll;
    const short* W2F = wAll + B_W2F / 2;
    const short* W3F = wAll + B_W3F / 2;

    bf16x8 Bb[2][4];
    bf16x8 B4b[2];
    auto load_k = [&](const short* wF, int kk, bf16x8* dst) {
        const short* src = wF + (size_t)kk * 2048;
#pragma unroll
        for (int j2 = 0; j2 < 4; ++j2)
            dst[j2] = *reinterpret_cast<const bf16x8*>(src + (j2 * 64 + lane) * 8);
    };
    auto load_b4 = [&](const short* wF, int kk, bf16x8* dst) {
        *dst = *reinterpret_cast<const bf16x8*>(wF + (size_t)kk * 2048 + (wv * 64 + lane) * 8);
    };

    load_k(W1F, 0, Bb[0]);

    // ---- stage X tile: rows px-4..px+11, cols py-4..py+9, zero-padded ----
    const short* Xn = X + (size_t)nl * (MXY * MXY) * CIN1;
    for (int i = tid; i < 448; i += 256) {
        int half = i & 1, pix = i >> 1;
        int row = pix / 14, col = pix - row * 14;
        int gx = px - 4 + row, gy = py - 4 + col;
        uint4 v = make_uint4(0u, 0u, 0u, 0u);
        if ((unsigned)gx < (unsigned)MXY && (unsigned)gy < (unsigned)MXY)
            v = *reinterpret_cast<const uint4*>(Xn + ((size_t)gx * MXY + gy) * CIN1 + half * 8);
        *reinterpret_cast<uint4*>(&s_u[pix * 24 + half * 8]) = v;
    }
    __syncthreads();  // barrier 1: X staged

    // ================= conv1: 5x5, X(16ch) -> Y1 12x10x64 =================
    {
        int prow[2], pcol[2];
#pragma unroll
        for (int i = 0; i < 2; ++i) {
            int p = wv * 32 + i * 16 + ml;
            if (p > 119) p = 119;  // pad px: duplicate compute, discarded
            prow[i] = p / 10; pcol[i] = p - prow[i] * 10;
        }
        floatx4 acc1[2][4] = {};

#pragma unroll
        for (int kk = 0; kk < 13; ++kk) {  // taps 0..25 (25 zero-padded)
            if (kk < 12) { load_k(W1F, kk + 1, Bb[(kk + 1) & 1]); }
            else         { load_k(W2F, 0, Bb[1]); load_b4(W2F, 0, &B4b[1]); }
            int tap = kk * 2 + (q >> 1);
            if (tap > 24) tap = 24;  // k-slots past tap24 have zero weights
            int chb = (q & 1) * 8;
            int dx = tap / 5, dy = tap - dx * 5;
            __builtin_amdgcn_s_setprio(1);
#pragma unroll
            for (int i = 0; i < 2; ++i) {
                bf16x8 A = *reinterpret_cast<const bf16x8*>(
                    &s_u[((prow[i] + dx) * 14 + (pcol[i] + dy)) * 24 + chb]);
#pragma unroll
                for (int j2 = 0; j2 < 4; ++j2)
                    acc1[i][j2] = __builtin_amdgcn_mfma_f32_16x16x32_bf16(
                        A, Bb[kk & 1][j2], acc1[i][j2], 0, 0, 0);
            }
            __builtin_amdgcn_s_setprio(0);
        }
        // epilogue: bias + relu, b64 paired-channel stores
        float b4[4];
#pragma unroll
        for (int j2 = 0; j2 < 4; ++j2) b4[j2] = bc1[j2 * 16 + ml];
#pragma unroll
        for (int i = 0; i < 2; ++i)
#pragma unroll
            for (int r = 0; r < 4; ++r) {
                int p = wv * 32 + i * 16 + q * 4 + r;
                if (p < 120) {
                    unsigned lo = (unsigned)(unsigned short)f2b(fmaxf(acc1[i][0][r] + b4[0], 0.f))
                                | ((unsigned)(unsigned short)f2b(fmaxf(acc1[i][1][r] + b4[1], 0.f)) << 16);
                    unsigned hi = (unsigned)(unsigned short)f2b(fmaxf(acc1[i][2][r] + b4[2], 0.f))
                                | ((unsigned)(unsigned short)f2b(fmaxf(acc1[i][3][r] + b4[3], 0.f)) << 16);
                    *reinterpret_cast<uint2*>(&s_Y1[p * 72 + ml * 4]) = make_uint2(lo, hi);
                }
            }
    }
    __syncthreads();  // barrier 2: Y1 complete; X dead

    // ===== conv2: 3x3, Y1 -> Y2 10x8x64 (tiles 0-3 owned, tile 4 n-split) ==
    {
        int prowA, pcolA, prowB, pcolB;
        {
            int p0 = wv * 16 + ml; prowA = p0 >> 3; pcolA = p0 & 7;
            int p1 = 64 + ml;      prowB = p1 >> 3; pcolB = p1 & 7;
        }
        floatx4 acc2[4] = {};
        floatx4 acc2s = {};

#pragma unroll
        for (int kk = 0; kk < 18; ++kk) {
            if (kk < 17) { load_k(W2F, kk + 1, Bb[kk & 1]); load_b4(W2F, kk + 1, &B4b[kk & 1]); }
            else         { load_k(W3F, 0, Bb[1]); }
            const int tap = kk >> 1;
            const int chb = (kk & 1) * 32 + q * 8;
            const int dx = tap / 3, dy = tap - (tap / 3) * 3;
            bf16x8 A0 = *reinterpret_cast<const bf16x8*>(
                &s_Y1[((prowA + dx) * 10 + (pcolA + dy)) * 72 + chb]);
            bf16x8 A4 = *reinterpret_cast<const bf16x8*>(
                &s_Y1[((prowB + dx) * 10 + (pcolB + dy)) * 72 + chb]);
            __builtin_amdgcn_s_setprio(1);
#pragma unroll
            for (int j2 = 0; j2 < 4; ++j2)
                acc2[j2] = __builtin_amdgcn_mfma_f32_16x16x32_bf16(A0, Bb[(kk + 1) & 1][j2], acc2[j2], 0, 0, 0);
            acc2s = __builtin_amdgcn_mfma_f32_16x16x32_bf16(A4, B4b[(kk + 1) & 1], acc2s, 0, 0, 0);
            __builtin_amdgcn_s_setprio(0);
        }
        // epilogue into s_u (X dead): own tile b64, shared tile scalar
        float b4[4];
#pragma unroll
        for (int j2 = 0; j2 < 4; ++j2) b4[j2] = bc2[j2 * 16 + ml];
#pragma unroll
        for (int r = 0; r < 4; ++r) {
            int p = wv * 16 + q * 4 + r;
            unsigned lo = (unsigned)(unsigned short)f2b(fmaxf(acc2[0][r] + b4[0], 0.f))
                        | ((unsigned)(unsigned short)f2b(fmaxf(acc2[1][r] + b4[1], 0.f)) << 16);
            unsigned hi = (unsigned)(unsigned short)f2b(fmaxf(acc2[2][r] + b4[2], 0.f))
                        | ((unsigned)(unsigned short)f2b(fmaxf(acc2[3][r] + b4[3], 0.f)) << 16);
            *reinterpret_cast<uint2*>(&s_u[p * 72 + ml * 4]) = make_uint2(lo, hi);
        }
        {
            float bt = bc2[wv * 16 + ml];
#pragma unroll
            for (int r = 0; r < 4; ++r) {
                int p = 64 + q * 4 + r;
                s_u[p * 72 + ml * 4 + wv] = f2b(fmaxf(acc2s[r] + bt, 0.f));
            }
        }
        if (tid < 64) s_feat[tid] = 0.f;
    }
    __syncthreads();  // barrier 3: Y2 complete

    // ====== conv3: 3x3, Y2 -> 8x6 masked room-sum (waves 0-2) ======
    if (wv < 3) {
        int p0 = wv * 16 + ml;
        int row3 = p0 / 6, col3 = p0 - (p0 / 6) * 6;
        floatx4 acc3[4] = {};

#pragma unroll
        for (int kk = 0; kk < 18; ++kk) {
            if (kk < 17) load_k(W3F, kk + 1, Bb[kk & 1]);
            const int tap = kk >> 1;
            const int chb = (kk & 1) * 32 + q * 8;
            const int dx = tap / 3, dy = tap - (tap / 3) * 3;
            bf16x8 A = *reinterpret_cast<const bf16x8*>(
                &s_u[((row3 + dx) * 8 + (col3 + dy)) * 72 + chb]);
            __builtin_amdgcn_s_setprio(1);
#pragma unroll
            for (int j2 = 0; j2 < 4; ++j2)
                acc3[j2] = __builtin_amdgcn_mfma_f32_16x16x32_bf16(A, Bb[(kk + 1) & 1][j2], acc3[j2], 0, 0, 0);
            __builtin_amdgcn_s_setprio(0);
        }
        float b4[4];
#pragma unroll
        for (int j2 = 0; j2 < 4; ++j2) b4[j2] = bc3[j2 * 16 + ml];
        float part[4] = {0.f, 0.f, 0.f, 0.f};
        const unsigned long long mk = rmask[room];
#pragma unroll
        for (int r = 0; r < 4; ++r) {
            int p = wv * 16 + q * 4 + r;  // == w*6+h == mask bit index
            if ((mk >> p) & 1ull) {
#pragma unroll
                for (int j2 = 0; j2 < 4; ++j2)
                    part[j2] += fmaxf(acc3[j2][r] + b4[j2], 0.f);
            }
        }
#pragma unroll
        for (int j2 = 0; j2 < 4; ++j2) {
            part[j2] += __shfl_xor(part[j2], 16);
            part[j2] += __shfl_xor(part[j2], 32);
        }
        if (q == 0) {
#pragma unroll
            for (int j2 = 0; j2 < 4; ++j2)
                atomicAdd(&s_feat[j2 * 16 + ml], part[j2]);  // 3 contenders
        }
    }
    __syncthreads();  // barrier 4
    if (tid < 64)
        feat[((size_t)n * RR + room) * 64 + tid] = s_feat[tid];
}

// ---------------------------------------------------------------------------
// Per-sample head: room MLP (64->128->128), room-sum, fc1, fc2.
// FEAT holds unnormalized masked sums; normalize by rinv here.
// ---------------------------------------------------------------------------
__global__ __launch_bounds__(256) void mlp_head(const float* __restrict__ feat,
                                                const float* __restrict__ HEAD,
                                                const float* __restrict__ rinv,
                                                const float* __restrict__ b1,
                                                const float* __restrict__ b2,
                                                const float* __restrict__ bf1,
                                                const float* __restrict__ bf2,
                                                float* __restrict__ outp)
{
    __shared__ __align__(16) float s_feat[RR * 64];
    __shared__ __align__(16) float s_h1[RR * 128];
    __shared__ __align__(16) float s_s[2 * 128];
    __shared__ __align__(16) float s_sf[128];
    __shared__ __align__(16) float s_t1[256];

    const int n = blockIdx.x;
    const int tid = threadIdx.x;
    const float* W1t = HEAD + F_WR1T;
    const float* W2t = HEAD + F_WR2T;
    const float* F1t = HEAD + F_F1T;
    const float* F2t = HEAD + F_F2T;

    for (int i = tid; i < RR * 64; i += 256)
        s_feat[i] = feat[(size_t)n * RR * 64 + i] * rinv[i >> 6];
    __syncthreads();

    const int o = tid & 127;
    const int rh = tid >> 7;

    float acc[16];
#pragma unroll
    for (int r = 0; r < 16; ++r) acc[r] = b1[o];
    for (int c4 = 0; c4 < 16; ++c4) {
        float w0 = W1t[(c4 * 4 + 0) * 128 + o];
        float w1 = W1t[(c4 * 4 + 1) * 128 + o];
        float w2 = W1t[(c4 * 4 + 2) * 128 + o];
        float w3 = W1t[(c4 * 4 + 3) * 128 + o];
#pragma unroll
        for (int r = 0; r < 16; ++r) {
            float4 f = *reinterpret_cast<const float4*>(&s_feat[(rh * 16 + r) * 64 + c4 * 4]);
            acc[r] += f.x * w0 + f.y * w1 + f.z * w2 + f.w * w3;
        }
    }
#pragma unroll
    for (int r = 0; r < 16; ++r) s_h1[(rh * 16 + r) * 128 + o] = fmaxf(acc[r], 0.f);
    __syncthreads();

#pragma unroll
    for (int r = 0; r < 16; ++r) acc[r] = b2[o];
    for (int c4 = 0; c4 < 32; ++c4) {
        float w0 = W2t[(c4 * 4 + 0) * 128 + o];
        float w1 = W2t[(c4 * 4 + 1) * 128 + o];
        float w2 = W2t[(c4 * 4 + 2) * 128 + o];
        float w3 = W2t[(c4 * 4 + 3) * 128 + o];
#pragma unroll
        for (int r = 0; r < 16; ++r) {
            float4 f = *reinterpret_cast<const float4*>(&s_h1[(rh * 16 + r) * 128 + c4 * 4]);
            acc[r] += f.x * w0 + f.y * w1 + f.z * w2 + f.w * w3;
        }
    }
    float ps = 0.f;
#pragma unroll
    for (int r = 0; r < 16; ++r) ps += fmaxf(acc[r], 0.f);
    s_s[rh * 128 + o] = ps;
    __syncthreads();
    if (tid < 128) s_sf[tid] = s_s[tid] + s_s[128 + tid];
    __syncthreads();

    {
        float a = bf1[tid];
        for (int c4 = 0; c4 < 32; ++c4) {
            float4 f = *reinterpret_cast<const float4*>(&s_sf[c4 * 4]);
            a += f.x * F1t[(c4 * 4 + 0) * 256 + tid];
            a += f.y * F1t[(c4 * 4 + 1) * 256 + tid];
            a += f.z * F1t[(c4 * 4 + 2) * 256 + tid];
            a += f.w * F1t[(c4 * 4 + 3) * 256 + tid];
        }
        s_t1[tid] = fmaxf(a, 0.f);
    }
    __syncthreads();

    {
        float a = bf2[tid];
        for (int c4 = 0; c4 < 64; ++c4) {
            float4 f = *reinterpret_cast<const float4*>(&s_t1[c4 * 4]);
            a += f.x * F2t[(c4 * 4 + 0) * 256 + tid];
            a += f.y * F2t[(c4 * 4 + 1) * 256 + tid];
            a += f.z * F2t[(c4 * 4 + 2) * 256 + tid];
            a += f.w * F2t[(c4 * 4 + 3) * 256 + tid];
        }
        outp[(size_t)n * 256 + tid] = a;
    }
}

// ---------------------------------------------------------------------------
extern "C" void kernel_launch(void* const* d_in, const int* in_sizes, int n_in,
                              void* d_out, int out_size, void* d_ws, size_t ws_size,
                              hipStream_t stream)
{
    const int* pos = (const int*)d_in[0];
    const float* rt = (const float*)d_in[1];
    const float* emb = (const float*)d_in[2];
    const float* w1 = (const float*)d_in[3];
    const float* bc1 = (const float*)d_in[4];
    const float* w2 = (const float*)d_in[5];
    const float* bc2 = (const float*)d_in[6];
    const float* w3 = (const float*)d_in[7];
    const float* bc3 = (const float*)d_in[8];
    const float* wr1 = (const float*)d_in[9];
    const float* br1 = (const float*)d_in[10];
    const float* wr2 = (const float*)d_in[11];
    const float* br2 = (const float*)d_in[12];
    const float* wf1 = (const float*)d_in[13];
    const float* bf1 = (const float*)d_in[14];
    const float* wf2 = (const float*)d_in[15];
    const float* bf2 = (const float*)d_in[16];
    float* out = (float*)d_out;
    char* ws = (char*)d_ws;

    prep_weights<<<880, 256, 0, stream>>>(w1, w2, w3, wr1, wr2, wf1, wf2, ws);
    prep_rooms<<<1, 64, 0, stream>>>(rt, ws);

    // largest batch chunk whose X buffer fits the workspace
    int nc = 16;
    const int cands[4] = {256, 128, 64, 32};
    for (int k = 0; k < 4; ++k) {
        size_t need = B_CHUNK + (size_t)cands[k] * PERN_BYTES;
        if (need <= ws_size) { nc = cands[k]; break; }
    }

    const short* WALL = (const short*)(ws + B_W1F);
    const unsigned long long* RMASK = (const unsigned long long*)(ws + B_RAUX);
    const float* RINV = (const float*)(ws + B_RINV);
    float* HEAD = (float*)(ws + B_HEAD);
    float* FEAT = (float*)(ws + B_FEAT);
    short* Xc = (short*)(ws + B_CHUNK);

    for (int n0 = 0; n0 < NB; n0 += nc) {
        build_x<<<dim3(21, nc), 256, 0, stream>>>(pos, rt, emb, Xc, n0);
        fused_conv<<<dim3(RR, nc), 256, 0, stream>>>(Xc, WALL, bc1, bc2, bc3,
                                                     pos, RMASK, FEAT, n0);
    }

    mlp_head<<<NB, 256, 0, stream>>>(FEAT, HEAD, RINV, br1, br2, bf1, bf2, out);
}

// Round 7
// 331.143 us; speedup vs baseline: 1.0553x; 1.0553x over previous
//
#include <hip/hip_runtime.h>
#include <hip/hip_bf16.h>
#include <cstddef>

// Problem constants
#define NB 256   // batch
#define RR 32    // rooms
#define WW 8     // room width
#define HH 6     // room height
#define MXY 72   // map extent
#define EMB 6
#define CIN1 16  // 9 + 1 + 6

typedef __bf16 bf16x8 __attribute__((ext_vector_type(8)));
typedef float floatx4 __attribute__((ext_vector_type(4)));

// --- Workspace layout (byte offsets) ---------------------------------------
// Conv weights packed per-kstep (2KB per kstep per ntile-group layout):
//   W1F: 13+1 ksteps [0,57344) ; W2F: 18 [57344,131072) ; W3F: 18 [131072,..)
static const size_t B_W1F  = 0;
static const size_t B_W2F  = 57344;
static const size_t B_W3F  = 131072;
static const size_t B_RAUX = 204800;    // room masks (32 u64)
static const size_t B_RINV = 205056;    // 1/room_size (32 f32)
static const size_t B_HEAD = 205312;    // fp32 head weights, 122880 floats
static const size_t F_WR1T = 0;         // (64,128)
static const size_t F_WR2T = 8192;      // (128,128)
static const size_t F_F1T  = 24576;     // (128,256)
static const size_t F_F2T  = 57344;     // (256,256)
static const size_t B_FEAT = 696832;    // (256,32,64) f32 = 2 MB
static const size_t B_CHUNK = 2793984;  // X buffer
static const size_t PERN_BYTES = 165888;  // X bf16 5184*16*2

__device__ inline short f2b(float f) {
    unsigned u = __builtin_bit_cast(unsigned, f);
    unsigned r = (u + 0x7fffu + ((u >> 16) & 1u)) >> 16;
    return (short)r;
}

// ---------------------------------------------------------------------------
// Prep: conv weights fp32 -> bf16 B-fragment order; head weights transposed.
// Fragment order: [kk][ntile][lane][j] ; virtual k = kk*32 + (lane>>4)*8 + j
// oc = ntile*16 + (lane&15).
// conv1: (tap,ci) natural. conv2/3: position cp -> channel (cp>>2)+(cp&3)*16
// (paired-channel layout Y1/Y2 are written in).
// ---------------------------------------------------------------------------
__global__ void prep_weights(const float* __restrict__ w1, const float* __restrict__ w2,
                             const float* __restrict__ w3, const float* __restrict__ wr1,
                             const float* __restrict__ wr2, const float* __restrict__ wf1,
                             const float* __restrict__ wf2, char* __restrict__ ws)
{
    short* W1F = (short*)(ws + B_W1F);
    short* W2F = (short*)(ws + B_W2F);
    short* W3F = (short*)(ws + B_W3F);
    float* HEAD = (float*)(ws + B_HEAD);

    int idx = blockIdx.x * 256 + threadIdx.x;
    if (idx < 28672) {  // conv1: 14 ksteps (padded), CIN=16, taps 0..24 real
        int j = idx & 7, lane = (idx >> 3) & 63, nt = (idx >> 9) & 3, kk = idx >> 11;
        int k = kk * 32 + (lane >> 4) * 8 + j;
        int oc = nt * 16 + (lane & 15);
        int tap = k >> 4, ci = k & 15;
        float v = (tap < 25) ? w1[(oc * 16 + ci) * 25 + tap] : 0.f;
        W1F[idx] = f2b(v);
        return;
    }
    idx -= 28672;
    if (idx < 36864) {  // conv2: 18 ksteps, CIN=64, 9 taps, permuted ci
        int j = idx & 7, lane = (idx >> 3) & 63, nt = (idx >> 9) & 3, kk = idx >> 11;
        int k = kk * 32 + (lane >> 4) * 8 + j;
        int oc = nt * 16 + (lane & 15);
        int tap = k >> 6, cp = k & 63;
        int ci = (cp >> 2) + (cp & 3) * 16;
        W2F[idx] = f2b(w2[(oc * 64 + ci) * 9 + tap]);
        return;
    }
    idx -= 36864;
    if (idx < 36864) {  // conv3, permuted ci
        int j = idx & 7, lane = (idx >> 3) & 63, nt = (idx >> 9) & 3, kk = idx >> 11;
        int k = kk * 32 + (lane >> 4) * 8 + j;
        int oc = nt * 16 + (lane & 15);
        int tap = k >> 6, cp = k & 63;
        int ci = (cp >> 2) + (cp & 3) * 16;
        W3F[idx] = f2b(w3[(oc * 64 + ci) * 9 + tap]);
        return;
    }
    idx -= 36864;
    if (idx < 8192)  { int o = idx & 127, c = idx >> 7; HEAD[F_WR1T + idx] = wr1[o * 64 + c]; return; }
    idx -= 8192;
    if (idx < 16384) { int o = idx & 127, c = idx >> 7; HEAD[F_WR2T + idx] = wr2[o * 128 + c]; return; }
    idx -= 16384;
    if (idx < 32768) { int o = idx & 255, c = idx >> 8; HEAD[F_F1T + idx] = wf1[o * 128 + c]; return; }
    idx -= 32768;
    if (idx < 65536) { int o = idx & 255, c = idx >> 8; HEAD[F_F2T + idx] = wf2[o * 256 + c]; return; }
}

// Room footprint bitmasks (48 bits) + 1/room_size.
__global__ void prep_rooms(const float* __restrict__ rt, char* __restrict__ ws)
{
    int r = threadIdx.x;
    if (r >= RR) return;
    unsigned long long m = 0ull;
    int cnt = 0;
    for (int j = 0; j < WW * HH; ++j)
        if (rt[r * 9 * 48 + j] != 0.f) { m |= (1ull << j); ++cnt; }
    ((unsigned long long*)(ws + B_RAUX))[r] = m;
    ((float*)(ws + B_RINV))[r] = 1.f / (float)cnt;
}

// ---------------------------------------------------------------------------
// Build X (nc, 72, 72, 16) NHWC bf16 — GATHER style.
// ---------------------------------------------------------------------------
__global__ __launch_bounds__(256) void build_x(const int* __restrict__ pos,
                                               const float* __restrict__ rt,
                                               const float* __restrict__ emb,
                                               short* __restrict__ X, int n0)
{
    const int nl = blockIdx.y;
    const int n = n0 + nl;
    const int p = blockIdx.x * 256 + threadIdx.x;

    __shared__ int s_px[RR], s_py[RR];
    __shared__ float s_emb[RR * EMB];
    if (threadIdx.x < RR) {
        s_px[threadIdx.x] = pos[(n * RR + threadIdx.x) * 2 + 0];
        s_py[threadIdx.x] = pos[(n * RR + threadIdx.x) * 2 + 1];
    }
    for (int i = threadIdx.x; i < RR * EMB; i += 256) s_emb[i] = emb[i];
    __syncthreads();
    if (p >= MXY * MXY) return;

    const int gx = p / MXY, gy = p - (p / MXY) * MXY;

    float acc[16];
#pragma unroll
    for (int c = 0; c < 16; ++c) acc[c] = 0.f;
    acc[9] = 1.f;

    for (int r = 0; r < RR; ++r) {
        int w = gx - s_px[r], h = gy - s_py[r];
        if ((unsigned)w < (unsigned)WW && (unsigned)h < (unsigned)HH) {
            int j = w * HH + h;
            const float* rr = rt + r * 9 * 48;
#pragma unroll
            for (int c = 0; c < 9; ++c) acc[c] += rr[c * 48 + j];
            float m = rr[j];  // channel 0 = room_map
#pragma unroll
            for (int e = 0; e < EMB; ++e) acc[10 + e] += s_emb[r * EMB + e] * m;
        }
    }

    short o[16];
#pragma unroll
    for (int c = 0; c < 16; ++c) o[c] = f2b(acc[c]);
    short* dst = X + ((size_t)nl * (MXY * MXY) + p) * CIN1;
    *reinterpret_cast<uint4*>(dst) = *reinterpret_cast<uint4*>(o);
    *reinterpret_cast<uint4*>(dst + 8) = *reinterpret_cast<uint4*>(o + 8);
}

// ---------------------------------------------------------------------------
// ROUND-7 FUSED CONV CHAIN — round-6 structure, spill-free.
//
// Round-6 post-mortem: WRITE_SIZE 91MB (~88 B/thread) = register SPILL —
// B4b ping-pong + chained prefetch exceeded the (256,5) 102-reg budget.
// Fixes (everything else identical for attribution):
//  * __launch_bounds__(256,4): 128-reg budget. Regs now cap occupancy at
//    4 blk/CU (LDS would allow 5); a spill round-trip (~200-900cy) on the
//    critical path costs more than the 5th block's TLP bought.
//  * B4 (conv2 n-split tile) loaded directly per kstep, no ping-pong:
//    removes 8 always-live VGPRs + the cross-iteration liveness chain.
//    L1-resident; 5 MFMAs/kstep + setprio cover the hit latency.
// ---------------------------------------------------------------------------
__global__ __launch_bounds__(256, 4) void fused_conv(const short* __restrict__ X,
    const short* __restrict__ wAll, const float* __restrict__ bc1,
    const float* __restrict__ bc2, const float* __restrict__ bc3,
    const int* __restrict__ pos, const unsigned long long* __restrict__ rmask,
    float* __restrict__ feat, int n0)
{
    __shared__ __align__(16) short s_Y1[120 * 72];  // 17280 B, paired-channel
    __shared__ __align__(16) short s_u[80 * 72];    // X[224][24] then Y2[80][72]
    __shared__ float s_feat[64];

    const int tid = threadIdx.x;
    const int lane = tid & 63;
    const int wv = tid >> 6;
    const int ml = lane & 15;
    const int q = lane >> 4;
    const int room = blockIdx.x;
    const int nl = blockIdx.y;
    const int n = n0 + nl;

    const int px = pos[(n * RR + room) * 2 + 0];
    const int py = pos[(n * RR + room) * 2 + 1];

    const short* W1F = wAll;
    const short* W2F = wAll + B_W2F / 2;
    const short* W3F = wAll + B_W3F / 2;

    bf16x8 Bb[2][4];
    auto load_k = [&](const short* wF, int kk, bf16x8* dst) {
        const short* src = wF + (size_t)kk * 2048;
#pragma unroll
        for (int j2 = 0; j2 < 4; ++j2)
            dst[j2] = *reinterpret_cast<const bf16x8*>(src + (j2 * 64 + lane) * 8);
    };

    load_k(W1F, 0, Bb[0]);

    // ---- stage X tile: rows px-4..px+11, cols py-4..py+9, zero-padded ----
    const short* Xn = X + (size_t)nl * (MXY * MXY) * CIN1;
    for (int i = tid; i < 448; i += 256) {
        int half = i & 1, pix = i >> 1;
        int row = pix / 14, col = pix - row * 14;
        int gx = px - 4 + row, gy = py - 4 + col;
        uint4 v = make_uint4(0u, 0u, 0u, 0u);
        if ((unsigned)gx < (unsigned)MXY && (unsigned)gy < (unsigned)MXY)
            v = *reinterpret_cast<const uint4*>(Xn + ((size_t)gx * MXY + gy) * CIN1 + half * 8);
        *reinterpret_cast<uint4*>(&s_u[pix * 24 + half * 8]) = v;
    }
    __syncthreads();  // barrier 1: X staged

    // ================= conv1: 5x5, X(16ch) -> Y1 12x10x64 =================
    {
        int prow[2], pcol[2];
#pragma unroll
        for (int i = 0; i < 2; ++i) {
            int p = wv * 32 + i * 16 + ml;
            if (p > 119) p = 119;  // pad px: duplicate compute, discarded
            prow[i] = p / 10; pcol[i] = p - prow[i] * 10;
        }
        floatx4 acc1[2][4] = {};

#pragma unroll
        for (int kk = 0; kk < 13; ++kk) {  // taps 0..25 (25 zero-padded)
            if (kk < 12) load_k(W1F, kk + 1, Bb[(kk + 1) & 1]);
            else         load_k(W2F, 0, Bb[1]);  // chain prefetch into conv2
            int tap = kk * 2 + (q >> 1);
            if (tap > 24) tap = 24;  // k-slots past tap24 have zero weights
            int chb = (q & 1) * 8;
            int dx = tap / 5, dy = tap - dx * 5;
            __builtin_amdgcn_s_setprio(1);
#pragma unroll
            for (int i = 0; i < 2; ++i) {
                bf16x8 A = *reinterpret_cast<const bf16x8*>(
                    &s_u[((prow[i] + dx) * 14 + (pcol[i] + dy)) * 24 + chb]);
#pragma unroll
                for (int j2 = 0; j2 < 4; ++j2)
                    acc1[i][j2] = __builtin_amdgcn_mfma_f32_16x16x32_bf16(
                        A, Bb[kk & 1][j2], acc1[i][j2], 0, 0, 0);
            }
            __builtin_amdgcn_s_setprio(0);
        }
        // epilogue: bias + relu, b64 paired-channel stores
        float b4[4];
#pragma unroll
        for (int j2 = 0; j2 < 4; ++j2) b4[j2] = bc1[j2 * 16 + ml];
#pragma unroll
        for (int i = 0; i < 2; ++i)
#pragma unroll
            for (int r = 0; r < 4; ++r) {
                int p = wv * 32 + i * 16 + q * 4 + r;
                if (p < 120) {
                    unsigned lo = (unsigned)(unsigned short)f2b(fmaxf(acc1[i][0][r] + b4[0], 0.f))
                                | ((unsigned)(unsigned short)f2b(fmaxf(acc1[i][1][r] + b4[1], 0.f)) << 16);
                    unsigned hi = (unsigned)(unsigned short)f2b(fmaxf(acc1[i][2][r] + b4[2], 0.f))
                                | ((unsigned)(unsigned short)f2b(fmaxf(acc1[i][3][r] + b4[3], 0.f)) << 16);
                    *reinterpret_cast<uint2*>(&s_Y1[p * 72 + ml * 4]) = make_uint2(lo, hi);
                }
            }
    }
    __syncthreads();  // barrier 2: Y1 complete; X dead

    // ===== conv2: 3x3, Y1 -> Y2 10x8x64 (tiles 0-3 owned, tile 4 n-split) ==
    {
        int prowA, pcolA, prowB, pcolB;
        {
            int p0 = wv * 16 + ml; prowA = p0 >> 3; pcolA = p0 & 7;
            int p1 = 64 + ml;      prowB = p1 >> 3; pcolB = p1 & 7;
        }
        floatx4 acc2[4] = {};
        floatx4 acc2s = {};

#pragma unroll
        for (int kk = 0; kk < 18; ++kk) {
            if (kk < 17) load_k(W2F, kk + 1, Bb[kk & 1]);
            else         load_k(W3F, 0, Bb[1]);  // chain prefetch into conv3
            // n-split tile's B frag: direct per-kstep load (L1-resident),
            // wave-uniform base (rule #20 safe), no ping-pong liveness.
            bf16x8 B4 = *reinterpret_cast<const bf16x8*>(
                W2F + (size_t)kk * 2048 + (wv * 64 + lane) * 8);
            const int tap = kk >> 1;
            const int chb = (kk & 1) * 32 + q * 8;
            const int dx = tap / 3, dy = tap - (tap / 3) * 3;
            bf16x8 A0 = *reinterpret_cast<const bf16x8*>(
                &s_Y1[((prowA + dx) * 10 + (pcolA + dy)) * 72 + chb]);
            bf16x8 A4 = *reinterpret_cast<const bf16x8*>(
                &s_Y1[((prowB + dx) * 10 + (pcolB + dy)) * 72 + chb]);
            __builtin_amdgcn_s_setprio(1);
#pragma unroll
            for (int j2 = 0; j2 < 4; ++j2)
                acc2[j2] = __builtin_amdgcn_mfma_f32_16x16x32_bf16(A0, Bb[(kk + 1) & 1][j2], acc2[j2], 0, 0, 0);
            acc2s = __builtin_amdgcn_mfma_f32_16x16x32_bf16(A4, B4, acc2s, 0, 0, 0);
            __builtin_amdgcn_s_setprio(0);
        }
        // epilogue into s_u (X dead): own tile b64, shared tile scalar
        float b4[4];
#pragma unroll
        for (int j2 = 0; j2 < 4; ++j2) b4[j2] = bc2[j2 * 16 + ml];
#pragma unroll
        for (int r = 0; r < 4; ++r) {
            int p = wv * 16 + q * 4 + r;
            unsigned lo = (unsigned)(unsigned short)f2b(fmaxf(acc2[0][r] + b4[0], 0.f))
                        | ((unsigned)(unsigned short)f2b(fmaxf(acc2[1][r] + b4[1], 0.f)) << 16);
            unsigned hi = (unsigned)(unsigned short)f2b(fmaxf(acc2[2][r] + b4[2], 0.f))
                        | ((unsigned)(unsigned short)f2b(fmaxf(acc2[3][r] + b4[3], 0.f)) << 16);
            *reinterpret_cast<uint2*>(&s_u[p * 72 + ml * 4]) = make_uint2(lo, hi);
        }
        {
            float bt = bc2[wv * 16 + ml];
#pragma unroll
            for (int r = 0; r < 4; ++r) {
                int p = 64 + q * 4 + r;
                s_u[p * 72 + ml * 4 + wv] = f2b(fmaxf(acc2s[r] + bt, 0.f));
            }
        }
        if (tid < 64) s_feat[tid] = 0.f;
    }
    __syncthreads();  // barrier 3: Y2 complete

    // ====== conv3: 3x3, Y2 -> 8x6 masked room-sum (waves 0-2) ======
    if (wv < 3) {
        int p0 = wv * 16 + ml;
        int row3 = p0 / 6, col3 = p0 - (p0 / 6) * 6;
        floatx4 acc3[4] = {};

#pragma unroll
        for (int kk = 0; kk < 18; ++kk) {
            if (kk < 17) load_k(W3F, kk + 1, Bb[kk & 1]);
            const int tap = kk >> 1;
            const int chb = (kk & 1) * 32 + q * 8;
            const int dx = tap / 3, dy = tap - (tap / 3) * 3;
            bf16x8 A = *reinterpret_cast<const bf16x8*>(
                &s_u[((row3 + dx) * 8 + (col3 + dy)) * 72 + chb]);
            __builtin_amdgcn_s_setprio(1);
#pragma unroll
            for (int j2 = 0; j2 < 4; ++j2)
                acc3[j2] = __builtin_amdgcn_mfma_f32_16x16x32_bf16(A, Bb[(kk + 1) & 1][j2], acc3[j2], 0, 0, 0);
            __builtin_amdgcn_s_setprio(0);
        }
        float b4[4];
#pragma unroll
        for (int j2 = 0; j2 < 4; ++j2) b4[j2] = bc3[j2 * 16 + ml];
        float part[4] = {0.f, 0.f, 0.f, 0.f};
        const unsigned long long mk = rmask[room];
#pragma unroll
        for (int r = 0; r < 4; ++r) {
            int p = wv * 16 + q * 4 + r;  // == w*6+h == mask bit index
            if ((mk >> p) & 1ull) {
#pragma unroll
                for (int j2 = 0; j2 < 4; ++j2)
                    part[j2] += fmaxf(acc3[j2][r] + b4[j2], 0.f);
            }
        }
#pragma unroll
        for (int j2 = 0; j2 < 4; ++j2) {
            part[j2] += __shfl_xor(part[j2], 16);
            part[j2] += __shfl_xor(part[j2], 32);
        }
        if (q == 0) {
#pragma unroll
            for (int j2 = 0; j2 < 4; ++j2)
                atomicAdd(&s_feat[j2 * 16 + ml], part[j2]);  // 3 contenders
        }
    }
    __syncthreads();  // barrier 4
    if (tid < 64)
        feat[((size_t)n * RR + room) * 64 + tid] = s_feat[tid];
}

// ---------------------------------------------------------------------------
// Per-sample head: room MLP (64->128->128), room-sum, fc1, fc2.
// FEAT holds unnormalized masked sums; normalize by rinv here.
// ---------------------------------------------------------------------------
__global__ __launch_bounds__(256) void mlp_head(const float* __restrict__ feat,
                                                const float* __restrict__ HEAD,
                                                const float* __restrict__ rinv,
                                                const float* __restrict__ b1,
                                                const float* __restrict__ b2,
                                                const float* __restrict__ bf1,
                                                const float* __restrict__ bf2,
                                                float* __restrict__ outp)
{
    __shared__ __align__(16) float s_feat[RR * 64];
    __shared__ __align__(16) float s_h1[RR * 128];
    __shared__ __align__(16) float s_s[2 * 128];
    __shared__ __align__(16) float s_sf[128];
    __shared__ __align__(16) float s_t1[256];

    const int n = blockIdx.x;
    const int tid = threadIdx.x;
    const float* W1t = HEAD + F_WR1T;
    const float* W2t = HEAD + F_WR2T;
    const float* F1t = HEAD + F_F1T;
    const float* F2t = HEAD + F_F2T;

    for (int i = tid; i < RR * 64; i += 256)
        s_feat[i] = feat[(size_t)n * RR * 64 + i] * rinv[i >> 6];
    __syncthreads();

    const int o = tid & 127;
    const int rh = tid >> 7;

    float acc[16];
#pragma unroll
    for (int r = 0; r < 16; ++r) acc[r] = b1[o];
    for (int c4 = 0; c4 < 16; ++c4) {
        float w0 = W1t[(c4 * 4 + 0) * 128 + o];
        float w1 = W1t[(c4 * 4 + 1) * 128 + o];
        float w2 = W1t[(c4 * 4 + 2) * 128 + o];
        float w3 = W1t[(c4 * 4 + 3) * 128 + o];
#pragma unroll
        for (int r = 0; r < 16; ++r) {
            float4 f = *reinterpret_cast<const float4*>(&s_feat[(rh * 16 + r) * 64 + c4 * 4]);
            acc[r] += f.x * w0 + f.y * w1 + f.z * w2 + f.w * w3;
        }
    }
#pragma unroll
    for (int r = 0; r < 16; ++r) s_h1[(rh * 16 + r) * 128 + o] = fmaxf(acc[r], 0.f);
    __syncthreads();

#pragma unroll
    for (int r = 0; r < 16; ++r) acc[r] = b2[o];
    for (int c4 = 0; c4 < 32; ++c4) {
        float w0 = W2t[(c4 * 4 + 0) * 128 + o];
        float w1 = W2t[(c4 * 4 + 1) * 128 + o];
        float w2 = W2t[(c4 * 4 + 2) * 128 + o];
        float w3 = W2t[(c4 * 4 + 3) * 128 + o];
#pragma unroll
        for (int r = 0; r < 16; ++r) {
            float4 f = *reinterpret_cast<const float4*>(&s_h1[(rh * 16 + r) * 128 + c4 * 4]);
            acc[r] += f.x * w0 + f.y * w1 + f.z * w2 + f.w * w3;
        }
    }
    float ps = 0.f;
#pragma unroll
    for (int r = 0; r < 16; ++r) ps += fmaxf(acc[r], 0.f);
    s_s[rh * 128 + o] = ps;
    __syncthreads();
    if (tid < 128) s_sf[tid] = s_s[tid] + s_s[128 + tid];
    __syncthreads();

    {
        float a = bf1[tid];
        for (int c4 = 0; c4 < 32; ++c4) {
            float4 f = *reinterpret_cast<const float4*>(&s_sf[c4 * 4]);
            a += f.x * F1t[(c4 * 4 + 0) * 256 + tid];
            a += f.y * F1t[(c4 * 4 + 1) * 256 + tid];
            a += f.z * F1t[(c4 * 4 + 2) * 256 + tid];
            a += f.w * F1t[(c4 * 4 + 3) * 256 + tid];
        }
        s_t1[tid] = fmaxf(a, 0.f);
    }
    __syncthreads();

    {
        float a = bf2[tid];
        for (int c4 = 0; c4 < 64; ++c4) {
            float4 f = *reinterpret_cast<const float4*>(&s_t1[c4 * 4]);
            a += f.x * F2t[(c4 * 4 + 0) * 256 + tid];
            a += f.y * F2t[(c4 * 4 + 1) * 256 + tid];
            a += f.z * F2t[(c4 * 4 + 2) * 256 + tid];
            a += f.w * F2t[(c4 * 4 + 3) * 256 + tid];
        }
        outp[(size_t)n * 256 + tid] = a;
    }
}

// ---------------------------------------------------------------------------
extern "C" void kernel_launch(void* const* d_in, const int* in_sizes, int n_in,
                              void* d_out, int out_size, void* d_ws, size_t ws_size,
                              hipStream_t stream)
{
    const int* pos = (const int*)d_in[0];
    const float* rt = (const float*)d_in[1];
    const float* emb = (const float*)d_in[2];
    const float* w1 = (const float*)d_in[3];
    const float* bc1 = (const float*)d_in[4];
    const float* w2 = (const float*)d_in[5];
    const float* bc2 = (const float*)d_in[6];
    const float* w3 = (const float*)d_in[7];
    const float* bc3 = (const float*)d_in[8];
    const float* wr1 = (const float*)d_in[9];
    const float* br1 = (const float*)d_in[10];
    const float* wr2 = (const float*)d_in[11];
    const float* br2 = (const float*)d_in[12];
    const float* wf1 = (const float*)d_in[13];
    const float* bf1 = (const float*)d_in[14];
    const float* wf2 = (const float*)d_in[15];
    const float* bf2 = (const float*)d_in[16];
    float* out = (float*)d_out;
    char* ws = (char*)d_ws;

    prep_weights<<<880, 256, 0, stream>>>(w1, w2, w3, wr1, wr2, wf1, wf2, ws);
    prep_rooms<<<1, 64, 0, stream>>>(rt, ws);

    // largest batch chunk whose X buffer fits the workspace
    int nc = 16;
    const int cands[4] = {256, 128, 64, 32};
    for (int k = 0; k < 4; ++k) {
        size_t need = B_CHUNK + (size_t)cands[k] * PERN_BYTES;
        if (need <= ws_size) { nc = cands[k]; break; }
    }

    const short* WALL = (const short*)(ws + B_W1F);
    const unsigned long long* RMASK = (const unsigned long long*)(ws + B_RAUX);
    const float* RINV = (const float*)(ws + B_RINV);
    float* HEAD = (float*)(ws + B_HEAD);
    float* FEAT = (float*)(ws + B_FEAT);
    short* Xc = (short*)(ws + B_CHUNK);

    for (int n0 = 0; n0 < NB; n0 += nc) {
        build_x<<<dim3(21, nc), 256, 0, stream>>>(pos, rt, emb, Xc, n0);
        fused_conv<<<dim3(RR, nc), 256, 0, stream>>>(Xc, WALL, bc1, bc2, bc3,
                                                     pos, RMASK, FEAT, n0);
    }

    mlp_head<<<NB, 256, 0, stream>>>(FEAT, HEAD, RINV, br1, br2, bf1, bf2, out);
}

// Round 8
// 312.113 us; speedup vs baseline: 1.1197x; 1.0610x over previous
//
#include <hip/hip_runtime.h>
#include <hip/hip_bf16.h>
#include <cstddef>

// Problem constants
#define NB 256   // batch
#define RR 32    // rooms
#define WW 8     // room width
#define HH 6     // room height
#define MXY 72   // map extent
#define EMB 6
#define CIN1 16  // 9 + 1 + 6

typedef __bf16 bf16x8 __attribute__((ext_vector_type(8)));
typedef float floatx4 __attribute__((ext_vector_type(4)));

// --- Workspace layout (byte offsets) ---------------------------------------
// Conv weights packed per-kstep (2KB per kstep per ntile-group layout):
//   W1F: 13+1 ksteps [0,57344) ; W2F: 18 [57344,131072) ; W3F: 18 [131072,..)
static const size_t B_W1F  = 0;
static const size_t B_W2F  = 57344;
static const size_t B_W3F  = 131072;
static const size_t B_RAUX = 204800;    // room masks (32 u64)
static const size_t B_RINV = 205056;    // 1/room_size (32 f32)
static const size_t B_HEAD = 205312;    // fp32 head weights, 122880 floats
static const size_t F_WR1T = 0;         // (64,128)
static const size_t F_WR2T = 8192;      // (128,128)
static const size_t F_F1T  = 24576;     // (128,256)
static const size_t F_F2T  = 57344;     // (256,256)
static const size_t B_FEAT = 696832;    // (256,32,64) f32 = 2 MB
static const size_t B_IMSK = 2793984;   // (256,32) u32 intersect masks (32 KB)

__device__ inline short f2b(float f) {
    unsigned u = __builtin_bit_cast(unsigned, f);
    unsigned r = (u + 0x7fffu + ((u >> 16) & 1u)) >> 16;
    return (short)r;
}

// ---------------------------------------------------------------------------
// Prep: conv weights fp32 -> bf16 B-fragment order; head weights transposed.
// Fragment order: [kk][ntile][lane][j] ; virtual k = kk*32 + (lane>>4)*8 + j
// oc = ntile*16 + (lane&15).
// conv1: (tap,ci) natural. conv2/3: position cp -> channel (cp>>2)+(cp&3)*16
// (paired-channel layout Y1/Y2 are written in).
// ---------------------------------------------------------------------------
__global__ void prep_weights(const float* __restrict__ w1, const float* __restrict__ w2,
                             const float* __restrict__ w3, const float* __restrict__ wr1,
                             const float* __restrict__ wr2, const float* __restrict__ wf1,
                             const float* __restrict__ wf2, char* __restrict__ ws)
{
    short* W1F = (short*)(ws + B_W1F);
    short* W2F = (short*)(ws + B_W2F);
    short* W3F = (short*)(ws + B_W3F);
    float* HEAD = (float*)(ws + B_HEAD);

    int idx = blockIdx.x * 256 + threadIdx.x;
    if (idx < 28672) {  // conv1: 14 ksteps (padded), CIN=16, taps 0..24 real
        int j = idx & 7, lane = (idx >> 3) & 63, nt = (idx >> 9) & 3, kk = idx >> 11;
        int k = kk * 32 + (lane >> 4) * 8 + j;
        int oc = nt * 16 + (lane & 15);
        int tap = k >> 4, ci = k & 15;
        float v = (tap < 25) ? w1[(oc * 16 + ci) * 25 + tap] : 0.f;
        W1F[idx] = f2b(v);
        return;
    }
    idx -= 28672;
    if (idx < 36864) {  // conv2: 18 ksteps, CIN=64, 9 taps, permuted ci
        int j = idx & 7, lane = (idx >> 3) & 63, nt = (idx >> 9) & 3, kk = idx >> 11;
        int k = kk * 32 + (lane >> 4) * 8 + j;
        int oc = nt * 16 + (lane & 15);
        int tap = k >> 6, cp = k & 63;
        int ci = (cp >> 2) + (cp & 3) * 16;
        W2F[idx] = f2b(w2[(oc * 64 + ci) * 9 + tap]);
        return;
    }
    idx -= 36864;
    if (idx < 36864) {  // conv3, permuted ci
        int j = idx & 7, lane = (idx >> 3) & 63, nt = (idx >> 9) & 3, kk = idx >> 11;
        int k = kk * 32 + (lane >> 4) * 8 + j;
        int oc = nt * 16 + (lane & 15);
        int tap = k >> 6, cp = k & 63;
        int ci = (cp >> 2) + (cp & 3) * 16;
        W3F[idx] = f2b(w3[(oc * 64 + ci) * 9 + tap]);
        return;
    }
    idx -= 36864;
    if (idx < 8192)  { int o = idx & 127, c = idx >> 7; HEAD[F_WR1T + idx] = wr1[o * 64 + c]; return; }
    idx -= 8192;
    if (idx < 16384) { int o = idx & 127, c = idx >> 7; HEAD[F_WR2T + idx] = wr2[o * 128 + c]; return; }
    idx -= 16384;
    if (idx < 32768) { int o = idx & 255, c = idx >> 8; HEAD[F_F1T + idx] = wf1[o * 128 + c]; return; }
    idx -= 32768;
    if (idx < 65536) { int o = idx & 255, c = idx >> 8; HEAD[F_F2T + idx] = wf2[o * 256 + c]; return; }
}

// Room footprint bitmasks (48 bits) + 1/room_size.
__global__ void prep_rooms(const float* __restrict__ rt, char* __restrict__ ws)
{
    int r = threadIdx.x;
    if (r >= RR) return;
    unsigned long long m = 0ull;
    int cnt = 0;
    for (int j = 0; j < WW * HH; ++j)
        if (rt[r * 9 * 48 + j] != 0.f) { m |= (1ull << j); ++cnt; }
    ((unsigned long long*)(ws + B_RAUX))[r] = m;
    ((float*)(ws + B_RINV))[r] = 1.f / (float)cnt;
}

// Per (sample, room): 32-bit mask of rooms intersecting the 16x14 X halo
// tile (rows px0-4..px0+11, cols py0-4..py0+9). ~4 bits set on average.
__global__ void prep_imask(const int* __restrict__ pos, unsigned* __restrict__ imask)
{
    const int n = blockIdx.x;
    const int r0 = threadIdx.x;  // 32
    const int px0 = pos[(n * RR + r0) * 2 + 0];
    const int py0 = pos[(n * RR + r0) * 2 + 1];
    unsigned m = 0;
    for (int r = 0; r < RR; ++r) {
        int rpx = pos[(n * RR + r) * 2 + 0];
        int rpy = pos[(n * RR + r) * 2 + 1];
        if (rpx >= px0 - 11 && rpx <= px0 + 11 && rpy >= py0 - 9 && rpy <= py0 + 9)
            m |= 1u << r;
    }
    imask[n * RR + r0] = m;
}

// ---------------------------------------------------------------------------
// ROUND-8 FUSED CONV CHAIN — X built IN-KERNEL (build_x deleted).
//
// Round-7 accounting: conv ~218us but ~110us was build_x + head + preps.
// build_x did a full-map 32-room scan + an 84MB X round-trip through HBM,
// yet fused_conv only consumes 224 px/block. Fix: threads 0-223 construct
// their tile pixel directly — walk the precomputed ~4-room intersect mask
// (uniform ctz loop; pos reads are block-uniform -> scalar loads),
// accumulate 16 channels fp32, f2b, two uint4 stores to s_u. Numerics
// identical to build_x (same fp32 gather -> bf16 round; ch9 = in-map flag,
// halo outside map stays zero).
//
// Conv body unchanged from round 7 (reg-B from global, spill-free (256,4)).
// ---------------------------------------------------------------------------
__global__ __launch_bounds__(256, 4) void fused_conv(
    const unsigned* __restrict__ imask, const float* __restrict__ rt,
    const float* __restrict__ emb, const short* __restrict__ wAll,
    const float* __restrict__ bc1, const float* __restrict__ bc2,
    const float* __restrict__ bc3, const int* __restrict__ pos,
    const unsigned long long* __restrict__ rmask, float* __restrict__ feat)
{
    __shared__ __align__(16) short s_Y1[120 * 72];  // 17280 B, paired-channel
    __shared__ __align__(16) short s_u[80 * 72];    // X[224][24] then Y2[80][72]
    __shared__ float s_feat[64];

    const int tid = threadIdx.x;
    const int lane = tid & 63;
    const int wv = tid >> 6;
    const int ml = lane & 15;
    const int q = lane >> 4;
    const int room = blockIdx.x;
    const int n = blockIdx.y;

    const int px = pos[(n * RR + room) * 2 + 0];
    const int py = pos[(n * RR + room) * 2 + 1];

    const short* W1F = wAll;
    const short* W2F = wAll + B_W2F / 2;
    const short* W3F = wAll + B_W3F / 2;

    bf16x8 Bb[2][4];
    auto load_k = [&](const short* wF, int kk, bf16x8* dst) {
        const short* src = wF + (size_t)kk * 2048;
#pragma unroll
        for (int j2 = 0; j2 < 4; ++j2)
            dst[j2] = *reinterpret_cast<const bf16x8*>(src + (j2 * 64 + lane) * 8);
    };

    load_k(W1F, 0, Bb[0]);

    // ---- build X tile in-kernel: threads 0..223, one 16-channel pixel ----
    {
        const unsigned mk0 = imask[n * RR + room];  // uniform
        if (tid < 224) {
            const int row = tid / 14, col = tid - (tid / 14) * 14;
            const int gx = px - 4 + row, gy = py - 4 + col;
            float a[16];
#pragma unroll
            for (int c = 0; c < 16; ++c) a[c] = 0.f;
            a[9] = ((unsigned)gx < (unsigned)MXY && (unsigned)gy < (unsigned)MXY) ? 1.f : 0.f;

            unsigned mm = mk0;
            while (mm) {
                const int r = __builtin_ctz(mm);
                mm &= mm - 1;
                const int rpx = pos[(n * RR + r) * 2 + 0];  // uniform -> s_load
                const int rpy = pos[(n * RR + r) * 2 + 1];
                const int w = gx - rpx, h = gy - rpy;
                if ((unsigned)w < (unsigned)WW && (unsigned)h < (unsigned)HH) {
                    const int j = w * HH + h;
                    const float* rr = rt + r * 9 * 48;
#pragma unroll
                    for (int c = 0; c < 9; ++c) a[c] += rr[c * 48 + j];
                    const float mv = rr[j];  // channel 0 = room_map
#pragma unroll
                    for (int e = 0; e < EMB; ++e) a[10 + e] += emb[r * EMB + e] * mv;
                }
            }
            short o[16];
#pragma unroll
            for (int c = 0; c < 16; ++c) o[c] = f2b(a[c]);
            *reinterpret_cast<uint4*>(&s_u[tid * 24 + 0]) = *reinterpret_cast<uint4*>(o);
            *reinterpret_cast<uint4*>(&s_u[tid * 24 + 8]) = *reinterpret_cast<uint4*>(o + 8);
        }
    }
    __syncthreads();  // barrier 1: X staged

    // ================= conv1: 5x5, X(16ch) -> Y1 12x10x64 =================
    {
        int prow[2], pcol[2];
#pragma unroll
        for (int i = 0; i < 2; ++i) {
            int p = wv * 32 + i * 16 + ml;
            if (p > 119) p = 119;  // pad px: duplicate compute, discarded
            prow[i] = p / 10; pcol[i] = p - prow[i] * 10;
        }
        floatx4 acc1[2][4] = {};

#pragma unroll
        for (int kk = 0; kk < 13; ++kk) {  // taps 0..25 (25 zero-padded)
            if (kk < 12) load_k(W1F, kk + 1, Bb[(kk + 1) & 1]);
            else         load_k(W2F, 0, Bb[1]);  // chain prefetch into conv2
            int tap = kk * 2 + (q >> 1);
            if (tap > 24) tap = 24;  // k-slots past tap24 have zero weights
            int chb = (q & 1) * 8;
            int dx = tap / 5, dy = tap - dx * 5;
            __builtin_amdgcn_s_setprio(1);
#pragma unroll
            for (int i = 0; i < 2; ++i) {
                bf16x8 A = *reinterpret_cast<const bf16x8*>(
                    &s_u[((prow[i] + dx) * 14 + (pcol[i] + dy)) * 24 + chb]);
#pragma unroll
                for (int j2 = 0; j2 < 4; ++j2)
                    acc1[i][j2] = __builtin_amdgcn_mfma_f32_16x16x32_bf16(
                        A, Bb[kk & 1][j2], acc1[i][j2], 0, 0, 0);
            }
            __builtin_amdgcn_s_setprio(0);
        }
        // epilogue: bias + relu, b64 paired-channel stores
        float b4[4];
#pragma unroll
        for (int j2 = 0; j2 < 4; ++j2) b4[j2] = bc1[j2 * 16 + ml];
#pragma unroll
        for (int i = 0; i < 2; ++i)
#pragma unroll
            for (int r = 0; r < 4; ++r) {
                int p = wv * 32 + i * 16 + q * 4 + r;
                if (p < 120) {
                    unsigned lo = (unsigned)(unsigned short)f2b(fmaxf(acc1[i][0][r] + b4[0], 0.f))
                                | ((unsigned)(unsigned short)f2b(fmaxf(acc1[i][1][r] + b4[1], 0.f)) << 16);
                    unsigned hi = (unsigned)(unsigned short)f2b(fmaxf(acc1[i][2][r] + b4[2], 0.f))
                                | ((unsigned)(unsigned short)f2b(fmaxf(acc1[i][3][r] + b4[3], 0.f)) << 16);
                    *reinterpret_cast<uint2*>(&s_Y1[p * 72 + ml * 4]) = make_uint2(lo, hi);
                }
            }
    }
    __syncthreads();  // barrier 2: Y1 complete; X dead

    // ===== conv2: 3x3, Y1 -> Y2 10x8x64 (tiles 0-3 owned, tile 4 n-split) ==
    {
        int prowA, pcolA, prowB, pcolB;
        {
            int p0 = wv * 16 + ml; prowA = p0 >> 3; pcolA = p0 & 7;
            int p1 = 64 + ml;      prowB = p1 >> 3; pcolB = p1 & 7;
        }
        floatx4 acc2[4] = {};
        floatx4 acc2s = {};

#pragma unroll
        for (int kk = 0; kk < 18; ++kk) {
            if (kk < 17) load_k(W2F, kk + 1, Bb[kk & 1]);
            else         load_k(W3F, 0, Bb[1]);  // chain prefetch into conv3
            // n-split tile's B frag: direct per-kstep load (L1-resident),
            // wave-uniform base (rule #20 safe), no ping-pong liveness.
            bf16x8 B4 = *reinterpret_cast<const bf16x8*>(
                W2F + (size_t)kk * 2048 + (wv * 64 + lane) * 8);
            const int tap = kk >> 1;
            const int chb = (kk & 1) * 32 + q * 8;
            const int dx = tap / 3, dy = tap - (tap / 3) * 3;
            bf16x8 A0 = *reinterpret_cast<const bf16x8*>(
                &s_Y1[((prowA + dx) * 10 + (pcolA + dy)) * 72 + chb]);
            bf16x8 A4 = *reinterpret_cast<const bf16x8*>(
                &s_Y1[((prowB + dx) * 10 + (pcolB + dy)) * 72 + chb]);
            __builtin_amdgcn_s_setprio(1);
#pragma unroll
            for (int j2 = 0; j2 < 4; ++j2)
                acc2[j2] = __builtin_amdgcn_mfma_f32_16x16x32_bf16(A0, Bb[(kk + 1) & 1][j2], acc2[j2], 0, 0, 0);
            acc2s = __builtin_amdgcn_mfma_f32_16x16x32_bf16(A4, B4, acc2s, 0, 0, 0);
            __builtin_amdgcn_s_setprio(0);
        }
        // epilogue into s_u (X dead): own tile b64, shared tile scalar
        float b4[4];
#pragma unroll
        for (int j2 = 0; j2 < 4; ++j2) b4[j2] = bc2[j2 * 16 + ml];
#pragma unroll
        for (int r = 0; r < 4; ++r) {
            int p = wv * 16 + q * 4 + r;
            unsigned lo = (unsigned)(unsigned short)f2b(fmaxf(acc2[0][r] + b4[0], 0.f))
                        | ((unsigned)(unsigned short)f2b(fmaxf(acc2[1][r] + b4[1], 0.f)) << 16);
            unsigned hi = (unsigned)(unsigned short)f2b(fmaxf(acc2[2][r] + b4[2], 0.f))
                        | ((unsigned)(unsigned short)f2b(fmaxf(acc2[3][r] + b4[3], 0.f)) << 16);
            *reinterpret_cast<uint2*>(&s_u[p * 72 + ml * 4]) = make_uint2(lo, hi);
        }
        {
            float bt = bc2[wv * 16 + ml];
#pragma unroll
            for (int r = 0; r < 4; ++r) {
                int p = 64 + q * 4 + r;
                s_u[p * 72 + ml * 4 + wv] = f2b(fmaxf(acc2s[r] + bt, 0.f));
            }
        }
        if (tid < 64) s_feat[tid] = 0.f;
    }
    __syncthreads();  // barrier 3: Y2 complete

    // ====== conv3: 3x3, Y2 -> 8x6 masked room-sum (waves 0-2) ======
    if (wv < 3) {
        int p0 = wv * 16 + ml;
        int row3 = p0 / 6, col3 = p0 - (p0 / 6) * 6;
        floatx4 acc3[4] = {};

#pragma unroll
        for (int kk = 0; kk < 18; ++kk) {
            if (kk < 17) load_k(W3F, kk + 1, Bb[kk & 1]);
            const int tap = kk >> 1;
            const int chb = (kk & 1) * 32 + q * 8;
            const int dx = tap / 3, dy = tap - (tap / 3) * 3;
            bf16x8 A = *reinterpret_cast<const bf16x8*>(
                &s_u[((row3 + dx) * 8 + (col3 + dy)) * 72 + chb]);
            __builtin_amdgcn_s_setprio(1);
#pragma unroll
            for (int j2 = 0; j2 < 4; ++j2)
                acc3[j2] = __builtin_amdgcn_mfma_f32_16x16x32_bf16(A, Bb[(kk + 1) & 1][j2], acc3[j2], 0, 0, 0);
            __builtin_amdgcn_s_setprio(0);
        }
        float b4[4];
#pragma unroll
        for (int j2 = 0; j2 < 4; ++j2) b4[j2] = bc3[j2 * 16 + ml];
        float part[4] = {0.f, 0.f, 0.f, 0.f};
        const unsigned long long mk = rmask[room];
#pragma unroll
        for (int r = 0; r < 4; ++r) {
            int p = wv * 16 + q * 4 + r;  // == w*6+h == mask bit index
            if ((mk >> p) & 1ull) {
#pragma unroll
                for (int j2 = 0; j2 < 4; ++j2)
                    part[j2] += fmaxf(acc3[j2][r] + b4[j2], 0.f);
            }
        }
#pragma unroll
        for (int j2 = 0; j2 < 4; ++j2) {
            part[j2] += __shfl_xor(part[j2], 16);
            part[j2] += __shfl_xor(part[j2], 32);
        }
        if (q == 0) {
#pragma unroll
            for (int j2 = 0; j2 < 4; ++j2)
                atomicAdd(&s_feat[j2 * 16 + ml], part[j2]);  // 3 contenders
        }
    }
    __syncthreads();  // barrier 4
    if (tid < 64)
        feat[((size_t)n * RR + room) * 64 + tid] = s_feat[tid];
}

// ---------------------------------------------------------------------------
// Per-sample head: room MLP (64->128->128), room-sum, fc1, fc2.
// FEAT holds unnormalized masked sums; normalize by rinv here.
// ---------------------------------------------------------------------------
__global__ __launch_bounds__(256) void mlp_head(const float* __restrict__ feat,
                                                const float* __restrict__ HEAD,
                                                const float* __restrict__ rinv,
                                                const float* __restrict__ b1,
                                                const float* __restrict__ b2,
                                                const float* __restrict__ bf1,
                                                const float* __restrict__ bf2,
                                                float* __restrict__ outp)
{
    __shared__ __align__(16) float s_feat[RR * 64];
    __shared__ __align__(16) float s_h1[RR * 128];
    __shared__ __align__(16) float s_s[2 * 128];
    __shared__ __align__(16) float s_sf[128];
    __shared__ __align__(16) float s_t1[256];

    const int n = blockIdx.x;
    const int tid = threadIdx.x;
    const float* W1t = HEAD + F_WR1T;
    const float* W2t = HEAD + F_WR2T;
    const float* F1t = HEAD + F_F1T;
    const float* F2t = HEAD + F_F2T;

    for (int i = tid; i < RR * 64; i += 256)
        s_feat[i] = feat[(size_t)n * RR * 64 + i] * rinv[i >> 6];
    __syncthreads();

    const int o = tid & 127;
    const int rh = tid >> 7;

    float acc[16];
#pragma unroll
    for (int r = 0; r < 16; ++r) acc[r] = b1[o];
    for (int c4 = 0; c4 < 16; ++c4) {
        float w0 = W1t[(c4 * 4 + 0) * 128 + o];
        float w1 = W1t[(c4 * 4 + 1) * 128 + o];
        float w2 = W1t[(c4 * 4 + 2) * 128 + o];
        float w3 = W1t[(c4 * 4 + 3) * 128 + o];
#pragma unroll
        for (int r = 0; r < 16; ++r) {
            float4 f = *reinterpret_cast<const float4*>(&s_feat[(rh * 16 + r) * 64 + c4 * 4]);
            acc[r] += f.x * w0 + f.y * w1 + f.z * w2 + f.w * w3;
        }
    }
#pragma unroll
    for (int r = 0; r < 16; ++r) s_h1[(rh * 16 + r) * 128 + o] = fmaxf(acc[r], 0.f);
    __syncthreads();

#pragma unroll
    for (int r = 0; r < 16; ++r) acc[r] = b2[o];
    for (int c4 = 0; c4 < 32; ++c4) {
        float w0 = W2t[(c4 * 4 + 0) * 128 + o];
        float w1 = W2t[(c4 * 4 + 1) * 128 + o];
        float w2 = W2t[(c4 * 4 + 2) * 128 + o];
        float w3 = W2t[(c4 * 4 + 3) * 128 + o];
#pragma unroll
        for (int r = 0; r < 16; ++r) {
            float4 f = *reinterpret_cast<const float4*>(&s_h1[(rh * 16 + r) * 128 + c4 * 4]);
            acc[r] += f.x * w0 + f.y * w1 + f.z * w2 + f.w * w3;
        }
    }
    float ps = 0.f;
#pragma unroll
    for (int r = 0; r < 16; ++r) ps += fmaxf(acc[r], 0.f);
    s_s[rh * 128 + o] = ps;
    __syncthreads();
    if (tid < 128) s_sf[tid] = s_s[tid] + s_s[128 + tid];
    __syncthreads();

    {
        float a = bf1[tid];
        for (int c4 = 0; c4 < 32; ++c4) {
            float4 f = *reinterpret_cast<const float4*>(&s_sf[c4 * 4]);
            a += f.x * F1t[(c4 * 4 + 0) * 256 + tid];
            a += f.y * F1t[(c4 * 4 + 1) * 256 + tid];
            a += f.z * F1t[(c4 * 4 + 2) * 256 + tid];
            a += f.w * F1t[(c4 * 4 + 3) * 256 + tid];
        }
        s_t1[tid] = fmaxf(a, 0.f);
    }
    __syncthreads();

    {
        float a = bf2[tid];
        for (int c4 = 0; c4 < 64; ++c4) {
            float4 f = *reinterpret_cast<const float4*>(&s_t1[c4 * 4]);
            a += f.x * F2t[(c4 * 4 + 0) * 256 + tid];
            a += f.y * F2t[(c4 * 4 + 1) * 256 + tid];
            a += f.z * F2t[(c4 * 4 + 2) * 256 + tid];
            a += f.w * F2t[(c4 * 4 + 3) * 256 + tid];
        }
        outp[(size_t)n * 256 + tid] = a;
    }
}

// ---------------------------------------------------------------------------
extern "C" void kernel_launch(void* const* d_in, const int* in_sizes, int n_in,
                              void* d_out, int out_size, void* d_ws, size_t ws_size,
                              hipStream_t stream)
{
    const int* pos = (const int*)d_in[0];
    const float* rt = (const float*)d_in[1];
    const float* emb = (const float*)d_in[2];
    const float* w1 = (const float*)d_in[3];
    const float* bc1 = (const float*)d_in[4];
    const float* w2 = (const float*)d_in[5];
    const float* bc2 = (const float*)d_in[6];
    const float* w3 = (const float*)d_in[7];
    const float* bc3 = (const float*)d_in[8];
    const float* wr1 = (const float*)d_in[9];
    const float* br1 = (const float*)d_in[10];
    const float* wr2 = (const float*)d_in[11];
    const float* br2 = (const float*)d_in[12];
    const float* wf1 = (const float*)d_in[13];
    const float* bf1 = (const float*)d_in[14];
    const float* wf2 = (const float*)d_in[15];
    const float* bf2 = (const float*)d_in[16];
    float* out = (float*)d_out;
    char* ws = (char*)d_ws;

    prep_weights<<<880, 256, 0, stream>>>(w1, w2, w3, wr1, wr2, wf1, wf2, ws);
    prep_rooms<<<1, 64, 0, stream>>>(rt, ws);

    const short* WALL = (const short*)(ws + B_W1F);
    const unsigned long long* RMASK = (const unsigned long long*)(ws + B_RAUX);
    const float* RINV = (const float*)(ws + B_RINV);
    float* HEAD = (float*)(ws + B_HEAD);
    float* FEAT = (float*)(ws + B_FEAT);
    unsigned* IMSK = (unsigned*)(ws + B_IMSK);

    prep_imask<<<NB, RR, 0, stream>>>(pos, IMSK);

    fused_conv<<<dim3(RR, NB), 256, 0, stream>>>(IMSK, rt, emb, WALL,
                                                 bc1, bc2, bc3, pos, RMASK, FEAT);

    mlp_head<<<NB, 256, 0, stream>>>(FEAT, HEAD, RINV, br1, br2, bf1, bf2, out);
}